// Round 5
// baseline (2202.609 us; speedup 1.0000x reference)
//
#include <hip/hip_runtime.h>

#define N_GRAPHS 32
#define NUM_NODES 2848
#define NTOT (N_GRAPHS * NUM_NODES)   // 91136
#define NE 1000000
#define KS 3
#define TL 5
#define HID 32
#define EPSV 1e-5f
#define SCAN_B 256
#define TILE_SHIFT 13                 // src tile = 8192 permuted nodes -> 512KB plane slice
#define NT 12                         // ceil(91136/8192)
#define NVN (NTOT * NT)               // 1093632
#define NBLK2 (NVN / SCAN_B)          // 4272
#define PL (NTOT * 16)                // uints per bf16 k-plane (16 uints = 32 bf16/node)
#define NB16 (NTOT / 16)              // 5696

// ---------------- bf16 pack/unpack ----------------

__device__ __forceinline__ float2 unpk(unsigned u) {
    return make_float2(__uint_as_float(u << 16), __uint_as_float(u & 0xffff0000u));
}
__device__ __forceinline__ unsigned bf16rn(float f) {
    unsigned x = __float_as_uint(f);
    return (x + 0x7fffu + ((x >> 16) & 1u)) >> 16;
}
__device__ __forceinline__ unsigned pk(float a, float b) {
    return bf16rn(a) | (bf16rn(b) << 16);
}

// ---------------- graph preprocessing ----------------

__global__ void k_deg(const int* __restrict__ col, const float* __restrict__ w,
                      float* __restrict__ deg, int* __restrict__ indeg) {
    int e = blockIdx.x * blockDim.x + threadIdx.x;
    if (e < NE) {
        int c = col[e];
        atomicAdd(&deg[c], w[e]);
        atomicAdd(&indeg[c], 1);
    }
}

__global__ void k_dis(float* deg) {
    int i = blockIdx.x * blockDim.x + threadIdx.x;
    if (i < NTOT) {
        float d = deg[i];
        deg[i] = (d > 0.f) ? rsqrtf(d) : 0.f;
    }
}

// degree histogram (64 bins, clamped)
__global__ void k_hist(const int* __restrict__ indeg, int* __restrict__ hist) {
    int n = blockIdx.x * blockDim.x + threadIdx.x;
    if (n < NTOT) atomicAdd(&hist[min(indeg[n], 63)], 1);
}

__global__ void k_binscan(const int* __restrict__ hist, int* __restrict__ bincur) {
    __shared__ int s[64];
    int t = threadIdx.x;
    s[t] = hist[t];
    __syncthreads();
    int acc = 0;
    for (int i = 0; i < t; ++i) acc += s[i];
    bincur[t] = acc;
}

__global__ void k_scatter(const int* __restrict__ indeg, int* __restrict__ bincur,
                          int* __restrict__ perm, int* __restrict__ invperm) {
    int n = blockIdx.x * blockDim.x + threadIdx.x;
    if (n < NTOT) {
        int b = min(indeg[n], 63);
        int pos = atomicAdd(&bincur[b], 1);
        perm[pos] = n;
        invperm[n] = pos;
    }
}

__global__ void k_xp(const float2* __restrict__ x, const int* __restrict__ perm,
                     float2* __restrict__ xp) {
    int i = blockIdx.x * blockDim.x + threadIdx.x;
    if (i < NTOT) xp[i] = x[perm[i]];
}

// count edges per (permuted dst, src tile)
__global__ void k_cnt2(const int* __restrict__ row, const int* __restrict__ col,
                       const int* __restrict__ invperm, int* __restrict__ indeg2) {
    int e = blockIdx.x * blockDim.x + threadIdx.x;
    if (e < NE) {
        int pc = invperm[col[e]];
        int pr = invperm[row[e]];
        atomicAdd(&indeg2[pc * NT + (pr >> TILE_SHIFT)], 1);
    }
}

// hierarchical exclusive scan of indeg2[NVN] -> offs2[NVN+1]
__global__ void k_scan1(const int* __restrict__ in, int* __restrict__ bsum) {
    __shared__ int s[SCAN_B];
    int i = blockIdx.x * SCAN_B + threadIdx.x;
    s[threadIdx.x] = in[i];
    __syncthreads();
    for (int st = SCAN_B / 2; st >= 1; st >>= 1) {
        if (threadIdx.x < st) s[threadIdx.x] += s[threadIdx.x + st];
        __syncthreads();
    }
    if (threadIdx.x == 0) bsum[blockIdx.x] = s[0];
}

__global__ void k_scan2(int* __restrict__ bsum) {
    __shared__ int s[1024];
    __shared__ int carry_s;
    int tid = threadIdx.x;
    if (tid == 0) carry_s = 0;
    __syncthreads();
    for (int c = 0; c < NBLK2; c += 1024) {
        int i = c + tid;
        int v = (i < NBLK2) ? bsum[i] : 0;
        s[tid] = v;
        __syncthreads();
        for (int off = 1; off < 1024; off <<= 1) {
            int a = (tid >= off) ? s[tid - off] : 0;
            __syncthreads();
            s[tid] += a;
            __syncthreads();
        }
        int incl = s[tid];
        int carry = carry_s;
        __syncthreads();
        if (i < NBLK2) bsum[i] = carry + incl - v;
        if (tid == 1023) carry_s = carry + incl;
        __syncthreads();
    }
}

__global__ void k_scan3(const int* __restrict__ in, const int* __restrict__ bsum,
                        int* __restrict__ offs) {
    __shared__ int s[SCAN_B];
    int i = blockIdx.x * SCAN_B + threadIdx.x;
    int v = in[i];
    s[threadIdx.x] = v;
    __syncthreads();
    for (int off = 1; off < SCAN_B; off <<= 1) {
        int a = (threadIdx.x >= off) ? s[threadIdx.x - off] : 0;
        __syncthreads();
        s[threadIdx.x] += a;
        __syncthreads();
    }
    offs[i] = bsum[blockIdx.x] + s[threadIdx.x] - v;
    if (i == 0) offs[NVN] = NE;
}

__global__ void k_fill(const int* __restrict__ row, const int* __restrict__ col,
                       const float* __restrict__ w, const float* __restrict__ dis,
                       const int* __restrict__ invperm, int* __restrict__ cursor,
                       int2* __restrict__ adj) {
    int e = blockIdx.x * blockDim.x + threadIdx.x;
    if (e < NE) {
        int r = row[e], c = col[e];
        float nm = dis[r] * w[e] * dis[c];
        int pr = invperm[r], pc = invperm[c];
        int p = atomicAdd(&cursor[pc * NT + (pr >> TILE_SHIFT)], 1);
        adj[p] = make_int2(pr, __float_as_int(nm));
    }
}

// ---------------- ARMA F=32 kernels (3 separate bf16 k-planes) ----------------

template<int FIN>
__global__ void k_init32(const float* __restrict__ xin, const float* __restrict__ iw,
                         unsigned* __restrict__ H) {
    int tid = blockIdx.x * blockDim.x + threadIdx.x;   // NTOT*16 exact
    int f2 = tid & 15;
    int n = tid >> 4;
    float a[KS][2] = {};
    const float2* iw2 = (const float2*)iw;
#pragma unroll
    for (int i = 0; i < FIN; ++i) {
        float xv = xin[n * FIN + i];
#pragma unroll
        for (int k = 0; k < KS; ++k) {
            float2 w = iw2[(k * FIN + i) * 16 + f2];
            a[k][0] += xv * w.x; a[k][1] += xv * w.y;
        }
    }
#pragma unroll
    for (int k = 0; k < KS; ++k)
        H[(size_t)k * PL + n * 16 + f2] = pk(a[k][0], a[k][1]);
}

// One k-plane per block (k = blockIdx.x / NB16); k-major order keeps one
// 5.8MB plane hot in L2 across the device at any instant.
template<int FIN, bool LAST>
__global__ __launch_bounds__(256) void k_prop32(
    const unsigned* __restrict__ H, const float* __restrict__ xin,
    const float* __restrict__ rw_t, const float* __restrict__ b_t,
    const float* __restrict__ W_t, const int* __restrict__ offs2,
    const int2* __restrict__ adj, unsigned* __restrict__ Hn,
    float* __restrict__ xo) {
    int tid = threadIdx.x;
    int f2 = tid & 15;
    int nl = tid >> 4;
    int bid = blockIdx.x;
    int k = bid / NB16;
    int node = (bid - k * NB16) * 16 + nl;

    const unsigned* Hk = H + (size_t)k * PL;
    float a0, a1;
    { float2 t = ((const float2*)(b_t + k * HID))[f2]; a0 = t.x; a1 = t.y; }
    const float2* rw2 = (const float2*)(rw_t + (size_t)k * FIN * HID);
#pragma unroll
    for (int i = 0; i < FIN; ++i) {
        float xv = xin[node * FIN + i];
        float2 r = rw2[i * 16 + f2];
        a0 += xv * r.x; a1 += xv * r.y;
    }

    int e0 = offs2[node * NT];
    int e1 = offs2[node * NT + NT];
    int e = e0;
    for (; e + 4 <= e1; e += 4) {
        int2 d0 = adj[e], d1 = adj[e + 1], d2 = adj[e + 2], d3 = adj[e + 3];
        unsigned p0 = Hk[(size_t)d0.x * 16 + f2];
        unsigned p1 = Hk[(size_t)d1.x * 16 + f2];
        unsigned p2 = Hk[(size_t)d2.x * 16 + f2];
        unsigned p3 = Hk[(size_t)d3.x * 16 + f2];
        float w0 = __int_as_float(d0.y), w1 = __int_as_float(d1.y);
        float w2 = __int_as_float(d2.y), w3 = __int_as_float(d3.y);
        float2 v;
        v = unpk(p0); a0 += w0 * v.x; a1 += w0 * v.y;
        v = unpk(p1); a0 += w1 * v.x; a1 += w1 * v.y;
        v = unpk(p2); a0 += w2 * v.x; a1 += w2 * v.y;
        v = unpk(p3); a0 += w3 * v.x; a1 += w3 * v.y;
    }
    for (; e < e1; ++e) {
        int2 d0 = adj[e];
        unsigned p0 = Hk[(size_t)d0.x * 16 + f2];
        float w0 = __int_as_float(d0.y);
        float2 v = unpk(p0);
        a0 += w0 * v.x; a1 += w0 * v.y;
    }
    a0 = fmaxf(a0, 0.f); a1 = fmaxf(a1, 0.f);

    if constexpr (LAST) {
        ((float2*)xo)[(size_t)k * (NTOT * 16) + node * 16 + f2] = make_float2(a0, a1);
    } else {
        __shared__ float so[16][34];
        so[nl][2 * f2] = a0; so[nl][2 * f2 + 1] = a1;
        __syncthreads();
        float h0 = 0.f, h1 = 0.f;
        const float2* W2 = (const float2*)(W_t + (size_t)k * HID * HID);
#pragma unroll
        for (int i = 0; i < HID; ++i) {
            float s = so[nl][i];
            float2 w = W2[i * 16 + f2];
            h0 += s * w.x; h1 += s * w.y;
        }
        Hn[(size_t)k * PL + node * 16 + f2] = pk(h0, h1);
    }
}

// ---------------- ARMA F=1 kernels (fp32 float4 plane, L2-resident) ----------------

__global__ void k_init1(const float* __restrict__ x, const float* __restrict__ iw,
                        float4* __restrict__ H) {
    int n = blockIdx.x * blockDim.x + threadIdx.x;
    if (n >= NTOT) return;
    float a0 = 0.f, a1 = 0.f, a2 = 0.f;
#pragma unroll
    for (int i = 0; i < HID; ++i) {
        float xv = x[n * HID + i];
        a0 += xv * iw[0 * HID + i];
        a1 += xv * iw[1 * HID + i];
        a2 += xv * iw[2 * HID + i];
    }
    H[n] = make_float4(a0, a1, a2, 0.f);
}

template<bool LAST>
__global__ void k_prop1(const float4* __restrict__ H, const float* __restrict__ xin,
                        const float* __restrict__ rw_t, const float* __restrict__ b_t,
                        const float* __restrict__ W_t, const int* __restrict__ offs2,
                        const int2* __restrict__ adj, const int* __restrict__ perm,
                        float* __restrict__ outp) {
    int node = blockIdx.x * blockDim.x + threadIdx.x;
    if (node >= NTOT) return;
    float a0 = b_t[0], a1 = b_t[1], a2 = b_t[2];
#pragma unroll
    for (int i = 0; i < HID; ++i) {
        float xv = xin[node * HID + i];
        a0 += xv * rw_t[0 * HID + i];
        a1 += xv * rw_t[1 * HID + i];
        a2 += xv * rw_t[2 * HID + i];
    }
    int e0 = offs2[node * NT];
    int e1 = offs2[node * NT + NT];
    int e = e0;
    for (; e + 4 <= e1; e += 4) {
        int2 d0 = adj[e], d1 = adj[e + 1], d2 = adj[e + 2], d3 = adj[e + 3];
        float4 h0 = H[d0.x], h1 = H[d1.x], h2 = H[d2.x], h3 = H[d3.x];
        float w0 = __int_as_float(d0.y), w1 = __int_as_float(d1.y);
        float w2 = __int_as_float(d2.y), w3 = __int_as_float(d3.y);
        a0 += w0 * h0.x; a1 += w0 * h0.y; a2 += w0 * h0.z;
        a0 += w1 * h1.x; a1 += w1 * h1.y; a2 += w1 * h1.z;
        a0 += w2 * h2.x; a1 += w2 * h2.y; a2 += w2 * h2.z;
        a0 += w3 * h3.x; a1 += w3 * h3.y; a2 += w3 * h3.z;
    }
    for (; e < e1; ++e) {
        int2 ed = adj[e];
        float4 h = H[ed.x];
        float w = __int_as_float(ed.y);
        a0 += w * h.x; a1 += w * h.y; a2 += w * h.z;
    }
    a0 = fmaxf(a0, 0.f); a1 = fmaxf(a1, 0.f); a2 = fmaxf(a2, 0.f);
    if constexpr (LAST) {
        outp[perm[node]] = (a0 + a1 + a2) * (1.f / 3.f);   // back to original order
    } else {
        ((float4*)outp)[node] = make_float4(a0 * W_t[0], a1 * W_t[1], a2 * W_t[2], 0.f);
    }
}

// ---------------- batchnorm (+relu) ----------------

// mean over 3 k-planes -> xa, and accumulate per-feature sums
__global__ void k_bnstats3(const float* __restrict__ x0, const float* __restrict__ x1,
                           const float* __restrict__ x2, float* __restrict__ xa,
                           float* __restrict__ stats) {
    __shared__ float s1[256];
    __shared__ float s2[256];
    int tid = threadIdx.x;
    int gid = blockIdx.x * blockDim.x + tid;
    int stride = gridDim.x * blockDim.x;
    float a = 0.f, b = 0.f;
    for (int i = gid; i < NTOT * HID; i += stride) {
        float v = (x0[i] + x1[i] + x2[i]) * (1.f / 3.f);
        xa[i] = v;
        a += v;
        b += v * v;
    }
    s1[tid] = a; s2[tid] = b;
    __syncthreads();
    for (int s = 128; s >= HID; s >>= 1) {
        if (tid < s) { s1[tid] += s1[tid + s]; s2[tid] += s2[tid + s]; }
        __syncthreads();
    }
    if (tid < HID) {
        atomicAdd(&stats[tid], s1[tid]);
        atomicAdd(&stats[HID + tid], s2[tid]);
    }
}

__global__ void k_bnstats(const float* __restrict__ x, float* __restrict__ stats, int F) {
    __shared__ float s1[256];
    __shared__ float s2[256];
    int tid = threadIdx.x;
    int gid = blockIdx.x * blockDim.x + tid;
    int stride = gridDim.x * blockDim.x;
    int total = NTOT * F;
    float a = 0.f, b = 0.f;
    for (int i = gid; i < total; i += stride) {
        float v = x[i];
        a += v;
        b += v * v;
    }
    s1[tid] = a; s2[tid] = b;
    __syncthreads();
    for (int s = 128; s >= F; s >>= 1) {
        if (tid < s) { s1[tid] += s1[tid + s]; s2[tid] += s2[tid + s]; }
        __syncthreads();
    }
    if (tid < F) {
        atomicAdd(&stats[tid], s1[tid]);
        atomicAdd(&stats[F + tid], s2[tid]);
    }
}

__global__ void k_bnapply(float* __restrict__ x, const float* __restrict__ stats,
                          const float* __restrict__ g, const float* __restrict__ be, int F) {
    int i = blockIdx.x * blockDim.x + threadIdx.x;
    int total = NTOT * F;
    if (i >= total) return;
    int f = i % F;
    float m = stats[f] * (1.f / (float)NTOT);
    float v = stats[F + f] * (1.f / (float)NTOT) - m * m;
    float y = (x[i] - m) * rsqrtf(v + EPSV) * g[f] + be[f];
    x[i] = fmaxf(y, 0.f);
}

// ---------------- classifier + per-graph max ----------------

__global__ void k_final(const float* __restrict__ h, const float* __restrict__ cw,
                        const float* __restrict__ cb, float* __restrict__ out) {
    __shared__ float smax[256];
    int g = blockIdx.x;
    float cwv = cw[0], cbv = cb[0];
    float mx = -INFINITY;
    for (int i = threadIdx.x; i < NUM_NODES; i += blockDim.x) {
        int nidx = g * NUM_NODES + i;
        float v = h[nidx] * cwv + cbv;
        out[nidx] = v;
        mx = fmaxf(mx, v);
    }
    smax[threadIdx.x] = mx;
    __syncthreads();
    for (int s = 128; s >= 1; s >>= 1) {
        if (threadIdx.x < s) smax[threadIdx.x] = fmaxf(smax[threadIdx.x], smax[threadIdx.x + s]);
        __syncthreads();
    }
    if (threadIdx.x == 0) out[NTOT + g] = smax[0];
}

// ---------------- host launch ----------------

extern "C" void kernel_launch(void* const* d_in, const int* in_sizes, int n_in,
                              void* d_out, int out_size, void* d_ws, size_t ws_size,
                              hipStream_t stream) {
    const float* x   = (const float*)d_in[0];
    const int*   ei  = (const int*)d_in[1];
    const int*   row = ei;
    const int*   col = ei + NE;
    const float* wts = (const float*)d_in[2];
    const float* iw1 = (const float*)d_in[4];
    const float* w1  = (const float*)d_in[5];
    const float* rw1 = (const float*)d_in[6];
    const float* b1  = (const float*)d_in[7];
    const float* g1  = (const float*)d_in[8];
    const float* be1 = (const float*)d_in[9];
    const float* iw2 = (const float*)d_in[10];
    const float* w2  = (const float*)d_in[11];
    const float* rw2 = (const float*)d_in[12];
    const float* b2  = (const float*)d_in[13];
    const float* g2  = (const float*)d_in[14];
    const float* be2 = (const float*)d_in[15];
    const float* iw3 = (const float*)d_in[16];
    const float* w3  = (const float*)d_in[17];
    const float* rw3 = (const float*)d_in[18];
    const float* b3  = (const float*)d_in[19];
    const float* g3  = (const float*)d_in[20];
    const float* be3 = (const float*)d_in[21];
    const float* cw  = (const float*)d_in[22];
    const float* cb  = (const float*)d_in[23];
    float* out = (float*)d_out;

    char* p = (char*)d_ws;
    auto alloc = [&](size_t bytes) {
        char* r = p;
        p += (bytes + 255) & ~(size_t)255;
        return r;
    };
    // zeroed as one contiguous range: deg .. indeg2
    float*    deg    = (float*)alloc((size_t)NTOT * 4);
    int*      indeg  = (int*)alloc((size_t)NTOT * 4);
    int*      hist   = (int*)alloc(64 * 4);
    int*      indeg2 = (int*)alloc((size_t)NVN * 4);
    char*     zend   = p;
    int*      bincur = (int*)alloc(64 * 4);
    int*      bsum   = (int*)alloc((size_t)NBLK2 * 4);
    int*      offs2  = (int*)alloc((size_t)(NVN + 1) * 4);
    int*      cursor = (int*)alloc((size_t)NVN * 4);
    int*      perm   = (int*)alloc((size_t)NTOT * 4);
    int*      invperm= (int*)alloc((size_t)NTOT * 4);
    int2*     adj    = (int2*)alloc((size_t)NE * 8);
    unsigned* HA     = (unsigned*)alloc((size_t)KS * PL * 4);
    unsigned* HB     = (unsigned*)alloc((size_t)KS * PL * 4);
    float2*   xp     = (float2*)alloc((size_t)NTOT * 8);
    float*    xa     = (float*)alloc((size_t)NTOT * HID * 4);
    float*    xb     = (float*)alloc((size_t)NTOT * HID * 4);
    float*    xo     = (float*)alloc((size_t)KS * NTOT * HID * 4);
    float*    xc     = (float*)alloc((size_t)NTOT * 4);
    float*    stats  = (float*)alloc(3 * 2 * HID * 4);
    if ((size_t)(p - (char*)d_ws) > ws_size) return;

    const int tb = 256;
    const int ebl = (NE + tb - 1) / tb;
    const int nbl = NTOT / tb;           // 356 exact
    const int g16 = NTOT * 16 / tb;      // 5696

    hipMemsetAsync(deg, 0, (size_t)(zend - (char*)deg), stream);
    hipMemsetAsync(stats, 0, (size_t)3 * 2 * HID * 4, stream);

    k_deg<<<ebl, tb, 0, stream>>>(col, wts, deg, indeg);
    k_dis<<<nbl, tb, 0, stream>>>(deg);
    k_hist<<<nbl, tb, 0, stream>>>(indeg, hist);
    k_binscan<<<1, 64, 0, stream>>>(hist, bincur);
    k_scatter<<<nbl, tb, 0, stream>>>(indeg, bincur, perm, invperm);
    k_xp<<<nbl, tb, 0, stream>>>((const float2*)x, perm, xp);
    k_cnt2<<<ebl, tb, 0, stream>>>(row, col, invperm, indeg2);
    k_scan1<<<NBLK2, SCAN_B, 0, stream>>>(indeg2, bsum);
    k_scan2<<<1, 1024, 0, stream>>>(bsum);
    k_scan3<<<NBLK2, SCAN_B, 0, stream>>>(indeg2, bsum, offs2);
    hipMemcpyAsync(cursor, offs2, (size_t)NVN * 4, hipMemcpyDeviceToDevice, stream);
    k_fill<<<ebl, tb, 0, stream>>>(row, col, wts, deg, invperm, cursor, adj);

    // ---- layer 1: 2 -> 32 ----
    {
        constexpr int FIN = 2, F = HID;
        const float* xin = (const float*)xp;
        k_init32<FIN><<<g16, tb, 0, stream>>>(xin, iw1, HA);
        const unsigned* Hc = HA; unsigned* Hn = HB;
        for (int t = 0; t < TL - 1; ++t) {
            k_prop32<FIN, false><<<KS * NB16, tb, 0, stream>>>(
                Hc, xin, rw1 + (size_t)t * KS * FIN * F, b1 + (size_t)t * KS * F,
                w1 + (size_t)t * KS * F * F, offs2, adj, Hn, nullptr);
            const unsigned* tmp = Hc; Hc = Hn; Hn = (unsigned*)tmp;
        }
        k_prop32<FIN, true><<<KS * NB16, tb, 0, stream>>>(
            Hc, xin, rw1 + (size_t)(TL - 1) * KS * FIN * F, b1 + (size_t)(TL - 1) * KS * F,
            nullptr, offs2, adj, nullptr, xo);
        k_bnstats3<<<256, tb, 0, stream>>>(xo, xo + (size_t)NTOT * HID,
                                           xo + (size_t)2 * NTOT * HID, xa, stats);
        k_bnapply<<<NTOT * HID / tb, tb, 0, stream>>>(xa, stats, g1, be1, HID);
    }
    // ---- layer 2: 32 -> 32 ----
    {
        constexpr int FIN = HID, F = HID;
        k_init32<FIN><<<g16, tb, 0, stream>>>(xa, iw2, HA);
        const unsigned* Hc = HA; unsigned* Hn = HB;
        for (int t = 0; t < TL - 1; ++t) {
            k_prop32<FIN, false><<<KS * NB16, tb, 0, stream>>>(
                Hc, xa, rw2 + (size_t)t * KS * FIN * F, b2 + (size_t)t * KS * F,
                w2 + (size_t)t * KS * F * F, offs2, adj, Hn, nullptr);
            const unsigned* tmp = Hc; Hc = Hn; Hn = (unsigned*)tmp;
        }
        k_prop32<FIN, true><<<KS * NB16, tb, 0, stream>>>(
            Hc, xa, rw2 + (size_t)(TL - 1) * KS * FIN * F, b2 + (size_t)(TL - 1) * KS * F,
            nullptr, offs2, adj, nullptr, xo);
        k_bnstats3<<<256, tb, 0, stream>>>(xo, xo + (size_t)NTOT * HID,
                                           xo + (size_t)2 * NTOT * HID, xb, stats + 2 * HID);
        k_bnapply<<<NTOT * HID / tb, tb, 0, stream>>>(xb, stats + 2 * HID, g2, be2, HID);
    }
    // ---- layer 3: 32 -> 1 ----
    {
        float4* HAf = (float4*)HA;
        float4* HBf = (float4*)HB;
        k_init1<<<nbl, tb, 0, stream>>>(xb, iw3, HAf);
        const float4* Hc = HAf; float4* Hn = HBf;
        for (int t = 0; t < TL - 1; ++t) {
            k_prop1<false><<<nbl, tb, 0, stream>>>(
                Hc, xb, rw3 + (size_t)t * KS * HID, b3 + (size_t)t * KS,
                w3 + (size_t)t * KS, offs2, adj, perm, (float*)Hn);
            const float4* tmp = Hc; Hc = Hn; Hn = (float4*)tmp;
        }
        k_prop1<true><<<nbl, tb, 0, stream>>>(
            Hc, xb, rw3 + (size_t)(TL - 1) * KS * HID, b3 + (size_t)(TL - 1) * KS,
            nullptr, offs2, adj, perm, xc);
        k_bnstats<<<256, tb, 0, stream>>>(xc, stats + 4 * HID, 1);
        k_bnapply<<<nbl, tb, 0, stream>>>(xc, stats + 4 * HID, g3, be3, 1);
    }

    k_final<<<N_GRAPHS, 256, 0, stream>>>(xc, cw, cb, out);
}

// Round 6
// 1631.657 us; speedup vs baseline: 1.3499x; 1.3499x over previous
//
#include <hip/hip_runtime.h>

#define N_GRAPHS 32
#define NUM_NODES 2848
#define NTOT (N_GRAPHS * NUM_NODES)   // 91136
#define NE 1000000
#define KS 3
#define TL 5
#define HID 32
#define EPSV 1e-5f
#define SCAN_B 256
#define NBLK (NTOT / SCAN_B)          // 356 (exact)
#define NBINS 64
#define CNTN (NBINS * NBLK)           // 22784 = 89*256 (exact)
#define CNTB (CNTN / SCAN_B)          // 89
#define PL (NTOT * 16)                // uints per bf16 32-feat plane (64B/node)
#define NB16 (NTOT / 16)              // 5696

// ---------------- bf16 pack/unpack ----------------

__device__ __forceinline__ float2 unpk(unsigned u) {
    return make_float2(__uint_as_float(u << 16), __uint_as_float(u & 0xffff0000u));
}
__device__ __forceinline__ unsigned bf16rn(float f) {
    unsigned x = __float_as_uint(f);
    return (x + 0x7fffu + ((x >> 16) & 1u)) >> 16;
}
__device__ __forceinline__ unsigned pk(float a, float b) {
    return bf16rn(a) | (bf16rn(b) << 16);
}

// ---------------- graph preprocessing ----------------

__global__ void k_deg(const int* __restrict__ col, const float* __restrict__ w,
                      float* __restrict__ deg, int* __restrict__ indeg) {
    int e = blockIdx.x * blockDim.x + threadIdx.x;
    if (e < NE) {
        int c = col[e];
        atomicAdd(&deg[c], w[e]);
        atomicAdd(&indeg[c], 1);
    }
}

__global__ void k_dis(float* deg) {
    int i = blockIdx.x * blockDim.x + threadIdx.x;
    if (i < NTOT) {
        float d = deg[i];
        deg[i] = (d > 0.f) ? rsqrtf(d) : 0.f;
    }
}

// per-block LDS histogram -> cnt[bin*NBLK + blk]  (bin-major, no global atomics)
__global__ void k_lhist(const int* __restrict__ indeg, int* __restrict__ cnt) {
    __shared__ int h[NBINS];
    int t = threadIdx.x;
    if (t < NBINS) h[t] = 0;
    __syncthreads();
    int n = blockIdx.x * SCAN_B + t;
    atomicAdd(&h[min(indeg[n], NBINS - 1)], 1);
    __syncthreads();
    if (t < NBINS) cnt[t * NBLK + blockIdx.x] = h[t];
}

// generic hierarchical scan helpers (block count * SCAN_B must equal n exactly)
__global__ void k_scan1(const int* __restrict__ in, int* __restrict__ bsum) {
    __shared__ int s[SCAN_B];
    int i = blockIdx.x * SCAN_B + threadIdx.x;
    s[threadIdx.x] = in[i];
    __syncthreads();
    for (int st = SCAN_B / 2; st >= 1; st >>= 1) {
        if (threadIdx.x < st) s[threadIdx.x] += s[threadIdx.x + st];
        __syncthreads();
    }
    if (threadIdx.x == 0) bsum[blockIdx.x] = s[0];
}

__global__ void k_scan2(int* __restrict__ bsum, int n) {
    __shared__ int s[512];
    int t = threadIdx.x;
    int v = (t < n) ? bsum[t] : 0;
    s[t] = v;
    __syncthreads();
    for (int off = 1; off < 512; off <<= 1) {
        int a = (t >= off) ? s[t - off] : 0;
        __syncthreads();
        s[t] += a;
        __syncthreads();
    }
    if (t < n) bsum[t] = s[t] - v;   // exclusive
}

__global__ void k_scan3(const int* __restrict__ in, const int* __restrict__ bsum,
                        int* __restrict__ out, int sentIdx, int sentVal) {
    __shared__ int s[SCAN_B];
    int i = blockIdx.x * SCAN_B + threadIdx.x;
    int v = in[i];
    s[threadIdx.x] = v;
    __syncthreads();
    for (int off = 1; off < SCAN_B; off <<= 1) {
        int a = (threadIdx.x >= off) ? s[threadIdx.x - off] : 0;
        __syncthreads();
        s[threadIdx.x] += a;
        __syncthreads();
    }
    out[i] = bsum[blockIdx.x] + s[threadIdx.x] - v;
    if (i == 0 && sentIdx >= 0) out[sentIdx] = sentVal;
}

// stable-enough counting-sort rank via LDS cursors
__global__ void k_rank(const int* __restrict__ indeg, const int* __restrict__ cnt,
                       int* __restrict__ perm, int* __restrict__ invperm,
                       int* __restrict__ indegp) {
    __shared__ int base[NBINS];
    __shared__ int cur[NBINS];
    int t = threadIdx.x;
    if (t < NBINS) { base[t] = cnt[t * NBLK + blockIdx.x]; cur[t] = 0; }
    __syncthreads();
    int n = blockIdx.x * SCAN_B + t;
    int dg = indeg[n];
    int b = min(dg, NBINS - 1);
    int pos = base[b] + atomicAdd(&cur[b], 1);
    perm[pos] = n;
    invperm[n] = pos;
    indegp[pos] = dg;
}

__global__ void k_xp(const float2* __restrict__ x, const int* __restrict__ perm,
                     float2* __restrict__ xp) {
    int i = blockIdx.x * blockDim.x + threadIdx.x;
    if (i < NTOT) xp[i] = x[perm[i]];
}

__global__ void k_fill(const int* __restrict__ row, const int* __restrict__ col,
                       const float* __restrict__ w, const float* __restrict__ dis,
                       const int* __restrict__ invperm, int* __restrict__ cursor,
                       int2* __restrict__ adj) {
    int e = blockIdx.x * blockDim.x + threadIdx.x;
    if (e < NE) {
        int r = row[e], c = col[e];
        float nm = dis[r] * w[e] * dis[c];
        int pr = invperm[r], pc = invperm[c];
        int p = atomicAdd(&cursor[pc], 1);
        adj[p] = make_int2(pr, __float_as_int(nm));
    }
}

// ---------------- ARMA F=32 kernels ----------------
// Planes store un-transformed out_t (bf16, 64B rows). Transform commutes with
// the linear gather: agg = gather(out)@W applied post-gather on dst node.

// layer-1 t=0: gather fp32 float2 x (729KB, L2-resident), all 3 k in one pass
__global__ __launch_bounds__(256) void k_prop0_2(
    const float2* __restrict__ xp, const float* __restrict__ iw,
    const float* __restrict__ rw0, const float* __restrict__ b0,
    const int* __restrict__ offs, const int2* __restrict__ adj,
    unsigned* __restrict__ OUT) {
    int tid = threadIdx.x;
    int f2 = tid & 15;
    int nl = tid >> 4;
    int node = blockIdx.x * 16 + nl;
    float p0 = 0.f, p1 = 0.f;
    int e0 = offs[node], e1 = offs[node + 1];
    int e = e0;
    for (; e + 4 <= e1; e += 4) {
        int2 d0 = adj[e], d1 = adj[e + 1], d2 = adj[e + 2], d3 = adj[e + 3];
        float2 x0 = xp[d0.x], x1 = xp[d1.x], x2 = xp[d2.x], x3 = xp[d3.x];
        float w0 = __int_as_float(d0.y), w1 = __int_as_float(d1.y);
        float w2 = __int_as_float(d2.y), w3 = __int_as_float(d3.y);
        p0 += w0 * x0.x + w1 * x1.x + w2 * x2.x + w3 * x3.x;
        p1 += w0 * x0.y + w1 * x1.y + w2 * x2.y + w3 * x3.y;
    }
    for (; e < e1; ++e) {
        int2 d = adj[e];
        float2 xs = xp[d.x];
        float w = __int_as_float(d.y);
        p0 += w * xs.x;
        p1 += w * xs.y;
    }
    float2 xn = xp[node];
#pragma unroll
    for (int k = 0; k < KS; ++k) {
        const float2* iw2 = (const float2*)(iw + k * 2 * HID);
        const float2* rw2 = (const float2*)(rw0 + k * 2 * HID);
        float2 wi0 = iw2[0 * 16 + f2], wi1 = iw2[1 * 16 + f2];
        float2 wr0 = rw2[0 * 16 + f2], wr1 = rw2[1 * 16 + f2];
        float2 bb = ((const float2*)(b0 + k * HID))[f2];
        float o0 = fmaxf(p0 * wi0.x + p1 * wi1.x + xn.x * wr0.x + xn.y * wr1.x + bb.x, 0.f);
        float o1 = fmaxf(p0 * wi0.y + p1 * wi1.y + xn.x * wr0.y + xn.y * wr1.y + bb.y, 0.f);
        OUT[(size_t)k * PL + node * 16 + f2] = pk(o0, o1);
    }
}

// layer-2 t=0: gather bf16 xplane once (5.8MB), all 3 k outputs in one pass
__global__ __launch_bounds__(256) void k_prop0_32(
    const unsigned* __restrict__ xplane, const float* __restrict__ xin,
    const float* __restrict__ iw, const float* __restrict__ rw0,
    const float* __restrict__ b0, const int* __restrict__ offs,
    const int2* __restrict__ adj, unsigned* __restrict__ OUT) {
    int tid = threadIdx.x;
    int f2 = tid & 15;
    int nl = tid >> 4;
    int node = blockIdx.x * 16 + nl;
    float p0 = 0.f, p1 = 0.f;
    int e0 = offs[node], e1 = offs[node + 1];
    int e = e0;
    for (; e + 4 <= e1; e += 4) {
        int2 d0 = adj[e], d1 = adj[e + 1], d2 = adj[e + 2], d3 = adj[e + 3];
        unsigned q0 = xplane[(size_t)d0.x * 16 + f2];
        unsigned q1 = xplane[(size_t)d1.x * 16 + f2];
        unsigned q2 = xplane[(size_t)d2.x * 16 + f2];
        unsigned q3 = xplane[(size_t)d3.x * 16 + f2];
        float w0 = __int_as_float(d0.y), w1 = __int_as_float(d1.y);
        float w2 = __int_as_float(d2.y), w3 = __int_as_float(d3.y);
        float2 v;
        v = unpk(q0); p0 += w0 * v.x; p1 += w0 * v.y;
        v = unpk(q1); p0 += w1 * v.x; p1 += w1 * v.y;
        v = unpk(q2); p0 += w2 * v.x; p1 += w2 * v.y;
        v = unpk(q3); p0 += w3 * v.x; p1 += w3 * v.y;
    }
    for (; e < e1; ++e) {
        int2 d = adj[e];
        unsigned q = xplane[(size_t)d.x * 16 + f2];
        float w = __int_as_float(d.y);
        float2 v = unpk(q);
        p0 += w * v.x; p1 += w * v.y;
    }
    __shared__ float so[16][34];
    so[nl][2 * f2] = p0;
    so[nl][2 * f2 + 1] = p1;
    __syncthreads();
#pragma unroll
    for (int k = 0; k < KS; ++k) {
        const float2* iw2 = (const float2*)(iw + (size_t)k * HID * HID);
        const float2* rw2 = (const float2*)(rw0 + (size_t)k * HID * HID);
        float2 bb = ((const float2*)(b0 + k * HID))[f2];
        float h0 = bb.x, h1 = bb.y;
#pragma unroll
        for (int i = 0; i < HID; ++i) {
            float s = so[nl][i];
            float xv = xin[node * HID + i];
            float2 wi = iw2[i * 16 + f2];
            float2 wr = rw2[i * 16 + f2];
            h0 += s * wi.x + xv * wr.x;
            h1 += s * wi.y + xv * wr.y;
        }
        OUT[(size_t)k * PL + node * 16 + f2] = pk(fmaxf(h0, 0.f), fmaxf(h1, 0.f));
    }
}

// t>=1: (k,node)-split, k-major block order keeps one 5.8MB plane L2-hot
template<int FIN, bool LAST>
__global__ __launch_bounds__(256) void k_propt(
    const unsigned* __restrict__ OUTprev, const float* __restrict__ xin,
    const float* __restrict__ rw_t, const float* __restrict__ b_t,
    const float* __restrict__ W_t, const int* __restrict__ offs,
    const int2* __restrict__ adj, unsigned* __restrict__ OUTnext,
    float* __restrict__ xo) {
    int tid = threadIdx.x;
    int f2 = tid & 15;
    int nl = tid >> 4;
    int bid = blockIdx.x;
    int k = bid / NB16;
    int node = (bid - k * NB16) * 16 + nl;

    const unsigned* Hk = OUTprev + (size_t)k * PL;
    float p0 = 0.f, p1 = 0.f;
    int e0 = offs[node], e1 = offs[node + 1];
    int e = e0;
    for (; e + 4 <= e1; e += 4) {
        int2 d0 = adj[e], d1 = adj[e + 1], d2 = adj[e + 2], d3 = adj[e + 3];
        unsigned q0 = Hk[(size_t)d0.x * 16 + f2];
        unsigned q1 = Hk[(size_t)d1.x * 16 + f2];
        unsigned q2 = Hk[(size_t)d2.x * 16 + f2];
        unsigned q3 = Hk[(size_t)d3.x * 16 + f2];
        float w0 = __int_as_float(d0.y), w1 = __int_as_float(d1.y);
        float w2 = __int_as_float(d2.y), w3 = __int_as_float(d3.y);
        float2 v;
        v = unpk(q0); p0 += w0 * v.x; p1 += w0 * v.y;
        v = unpk(q1); p0 += w1 * v.x; p1 += w1 * v.y;
        v = unpk(q2); p0 += w2 * v.x; p1 += w2 * v.y;
        v = unpk(q3); p0 += w3 * v.x; p1 += w3 * v.y;
    }
    for (; e < e1; ++e) {
        int2 d = adj[e];
        unsigned q = Hk[(size_t)d.x * 16 + f2];
        float w = __int_as_float(d.y);
        float2 v = unpk(q);
        p0 += w * v.x; p1 += w * v.y;
    }

    __shared__ float so[16][34];
    so[nl][2 * f2] = p0;
    so[nl][2 * f2 + 1] = p1;
    __syncthreads();

    const float2* W2 = (const float2*)(W_t + (size_t)k * HID * HID);
    const float2* rw2 = (const float2*)(rw_t + (size_t)k * FIN * HID);
    float2 bb = ((const float2*)(b_t + k * HID))[f2];
    float h0 = bb.x, h1 = bb.y;
#pragma unroll
    for (int i = 0; i < HID; ++i) {
        float s = so[nl][i];
        float2 wv = W2[i * 16 + f2];
        h0 += s * wv.x;
        h1 += s * wv.y;
    }
#pragma unroll
    for (int i = 0; i < FIN; ++i) {
        float xv = xin[node * FIN + i];
        float2 r = rw2[i * 16 + f2];
        h0 += xv * r.x;
        h1 += xv * r.y;
    }
    h0 = fmaxf(h0, 0.f);
    h1 = fmaxf(h1, 0.f);

    if constexpr (LAST) {
        ((float2*)xo)[(size_t)k * (NTOT * 16) + node * 16 + f2] = make_float2(h0, h1);
    } else {
        OUTnext[(size_t)k * PL + node * 16 + f2] = pk(h0, h1);
    }
}

// ---------------- ARMA F=1 kernels (fp32 float4 plane, L2-resident) ----------------

__global__ void k_init1(const float* __restrict__ x, const float* __restrict__ iw,
                        float4* __restrict__ H) {
    int n = blockIdx.x * blockDim.x + threadIdx.x;
    if (n >= NTOT) return;
    float a0 = 0.f, a1 = 0.f, a2 = 0.f;
#pragma unroll
    for (int i = 0; i < HID; ++i) {
        float xv = x[n * HID + i];
        a0 += xv * iw[0 * HID + i];
        a1 += xv * iw[1 * HID + i];
        a2 += xv * iw[2 * HID + i];
    }
    H[n] = make_float4(a0, a1, a2, 0.f);
}

template<bool LAST>
__global__ void k_prop1(const float4* __restrict__ H, const float* __restrict__ xin,
                        const float* __restrict__ rw_t, const float* __restrict__ b_t,
                        const float* __restrict__ W_t, const int* __restrict__ offs,
                        const int2* __restrict__ adj, const int* __restrict__ perm,
                        float* __restrict__ outp) {
    int node = blockIdx.x * blockDim.x + threadIdx.x;
    if (node >= NTOT) return;
    float a0 = b_t[0], a1 = b_t[1], a2 = b_t[2];
#pragma unroll
    for (int i = 0; i < HID; ++i) {
        float xv = xin[node * HID + i];
        a0 += xv * rw_t[0 * HID + i];
        a1 += xv * rw_t[1 * HID + i];
        a2 += xv * rw_t[2 * HID + i];
    }
    int e0 = offs[node], e1 = offs[node + 1];
    int e = e0;
    for (; e + 4 <= e1; e += 4) {
        int2 d0 = adj[e], d1 = adj[e + 1], d2 = adj[e + 2], d3 = adj[e + 3];
        float4 h0 = H[d0.x], h1 = H[d1.x], h2 = H[d2.x], h3 = H[d3.x];
        float w0 = __int_as_float(d0.y), w1 = __int_as_float(d1.y);
        float w2 = __int_as_float(d2.y), w3 = __int_as_float(d3.y);
        a0 += w0 * h0.x; a1 += w0 * h0.y; a2 += w0 * h0.z;
        a0 += w1 * h1.x; a1 += w1 * h1.y; a2 += w1 * h1.z;
        a0 += w2 * h2.x; a1 += w2 * h2.y; a2 += w2 * h2.z;
        a0 += w3 * h3.x; a1 += w3 * h3.y; a2 += w3 * h3.z;
    }
    for (; e < e1; ++e) {
        int2 ed = adj[e];
        float4 h = H[ed.x];
        float w = __int_as_float(ed.y);
        a0 += w * h.x; a1 += w * h.y; a2 += w * h.z;
    }
    a0 = fmaxf(a0, 0.f); a1 = fmaxf(a1, 0.f); a2 = fmaxf(a2, 0.f);
    if constexpr (LAST) {
        outp[perm[node]] = (a0 + a1 + a2) * (1.f / 3.f);   // back to original order
    } else {
        ((float4*)outp)[node] = make_float4(a0 * W_t[0], a1 * W_t[1], a2 * W_t[2], 0.f);
    }
}

// ---------------- batchnorm (+relu) ----------------

__global__ void k_bnstats3(const float* __restrict__ x0, const float* __restrict__ x1,
                           const float* __restrict__ x2, float* __restrict__ xa,
                           float* __restrict__ stats) {
    __shared__ float s1[256];
    __shared__ float s2[256];
    int tid = threadIdx.x;
    int gid = blockIdx.x * blockDim.x + tid;
    int stride = gridDim.x * blockDim.x;
    float a = 0.f, b = 0.f;
    for (int i = gid; i < NTOT * HID; i += stride) {
        float v = (x0[i] + x1[i] + x2[i]) * (1.f / 3.f);
        xa[i] = v;
        a += v;
        b += v * v;
    }
    s1[tid] = a; s2[tid] = b;
    __syncthreads();
    for (int s = 128; s >= HID; s >>= 1) {
        if (tid < s) { s1[tid] += s1[tid + s]; s2[tid] += s2[tid + s]; }
        __syncthreads();
    }
    if (tid < HID) {
        atomicAdd(&stats[tid], s1[tid]);
        atomicAdd(&stats[HID + tid], s2[tid]);
    }
}

__global__ void k_bnstats(const float* __restrict__ x, float* __restrict__ stats, int F) {
    __shared__ float s1[256];
    __shared__ float s2[256];
    int tid = threadIdx.x;
    int gid = blockIdx.x * blockDim.x + tid;
    int stride = gridDim.x * blockDim.x;
    int total = NTOT * F;
    float a = 0.f, b = 0.f;
    for (int i = gid; i < total; i += stride) {
        float v = x[i];
        a += v;
        b += v * v;
    }
    s1[tid] = a; s2[tid] = b;
    __syncthreads();
    for (int s = 128; s >= F; s >>= 1) {
        if (tid < s) { s1[tid] += s1[tid + s]; s2[tid] += s2[tid + s]; }
        __syncthreads();
    }
    if (tid < F) {
        atomicAdd(&stats[tid], s1[tid]);
        atomicAdd(&stats[F + tid], s2[tid]);
    }
}

// bnapply + relu; optionally also emit bf16 plane (gather source for next layer)
__global__ void k_bnapply(float* __restrict__ x, const float* __restrict__ stats,
                          const float* __restrict__ g, const float* __restrict__ be,
                          int F, unsigned short* __restrict__ xbf) {
    int i = blockIdx.x * blockDim.x + threadIdx.x;
    int total = NTOT * F;
    if (i >= total) return;
    int f = i % F;
    float m = stats[f] * (1.f / (float)NTOT);
    float v = stats[F + f] * (1.f / (float)NTOT) - m * m;
    float y = (x[i] - m) * rsqrtf(v + EPSV) * g[f] + be[f];
    y = fmaxf(y, 0.f);
    x[i] = y;
    if (xbf) xbf[i] = (unsigned short)bf16rn(y);
}

// ---------------- classifier + per-graph max ----------------

__global__ void k_final(const float* __restrict__ h, const float* __restrict__ cw,
                        const float* __restrict__ cb, float* __restrict__ out) {
    __shared__ float smax[256];
    int g = blockIdx.x;
    float cwv = cw[0], cbv = cb[0];
    float mx = -INFINITY;
    for (int i = threadIdx.x; i < NUM_NODES; i += blockDim.x) {
        int nidx = g * NUM_NODES + i;
        float v = h[nidx] * cwv + cbv;
        out[nidx] = v;
        mx = fmaxf(mx, v);
    }
    smax[threadIdx.x] = mx;
    __syncthreads();
    for (int s = 128; s >= 1; s >>= 1) {
        if (threadIdx.x < s) smax[threadIdx.x] = fmaxf(smax[threadIdx.x], smax[threadIdx.x + s]);
        __syncthreads();
    }
    if (threadIdx.x == 0) out[NTOT + g] = smax[0];
}

// ---------------- host launch ----------------

extern "C" void kernel_launch(void* const* d_in, const int* in_sizes, int n_in,
                              void* d_out, int out_size, void* d_ws, size_t ws_size,
                              hipStream_t stream) {
    const float* x   = (const float*)d_in[0];
    const int*   ei  = (const int*)d_in[1];
    const int*   row = ei;
    const int*   col = ei + NE;
    const float* wts = (const float*)d_in[2];
    const float* iw1 = (const float*)d_in[4];
    const float* w1  = (const float*)d_in[5];
    const float* rw1 = (const float*)d_in[6];
    const float* b1  = (const float*)d_in[7];
    const float* g1  = (const float*)d_in[8];
    const float* be1 = (const float*)d_in[9];
    const float* iw2 = (const float*)d_in[10];
    const float* w2  = (const float*)d_in[11];
    const float* rw2 = (const float*)d_in[12];
    const float* b2  = (const float*)d_in[13];
    const float* g2  = (const float*)d_in[14];
    const float* be2 = (const float*)d_in[15];
    const float* iw3 = (const float*)d_in[16];
    const float* w3  = (const float*)d_in[17];
    const float* rw3 = (const float*)d_in[18];
    const float* b3  = (const float*)d_in[19];
    const float* g3  = (const float*)d_in[20];
    const float* be3 = (const float*)d_in[21];
    const float* cw  = (const float*)d_in[22];
    const float* cb  = (const float*)d_in[23];
    float* out = (float*)d_out;

    char* p = (char*)d_ws;
    auto alloc = [&](size_t bytes) {
        char* r = p;
        p += (bytes + 255) & ~(size_t)255;
        return r;
    };
    // contiguous zero range: deg, indeg, cnt
    float*    deg    = (float*)alloc((size_t)NTOT * 4);
    int*      indeg  = (int*)alloc((size_t)NTOT * 4);
    int*      cnt    = (int*)alloc((size_t)CNTN * 4);
    char*     zend   = p;
    int*      bsum   = (int*)alloc((size_t)NBLK * 4);
    int*      offs   = (int*)alloc((size_t)(NTOT + 1) * 4);
    int*      cursor = (int*)alloc((size_t)NTOT * 4);
    int*      perm   = (int*)alloc((size_t)NTOT * 4);
    int*      invperm= (int*)alloc((size_t)NTOT * 4);
    int*      indegp = (int*)alloc((size_t)NTOT * 4);
    int2*     adj    = (int2*)alloc((size_t)NE * 8);
    unsigned* OUTA   = (unsigned*)alloc((size_t)KS * PL * 4);
    unsigned* OUTB   = (unsigned*)alloc((size_t)KS * PL * 4);
    unsigned* xplane = (unsigned*)alloc((size_t)PL * 4);
    float2*   xp     = (float2*)alloc((size_t)NTOT * 8);
    float*    xa     = (float*)alloc((size_t)NTOT * HID * 4);
    float*    xb     = (float*)alloc((size_t)NTOT * HID * 4);
    float*    xo     = (float*)alloc((size_t)KS * NTOT * HID * 4);
    float*    xc     = (float*)alloc((size_t)NTOT * 4);
    float*    stats  = (float*)alloc(3 * 2 * HID * 4);
    if ((size_t)(p - (char*)d_ws) > ws_size) return;

    const int tb = 256;
    const int ebl = (NE + tb - 1) / tb;
    const int nbl = NTOT / tb;           // 356 exact

    hipMemsetAsync(deg, 0, (size_t)(zend - (char*)deg), stream);
    hipMemsetAsync(stats, 0, (size_t)3 * 2 * HID * 4, stream);

    k_deg<<<ebl, tb, 0, stream>>>(col, wts, deg, indeg);
    k_dis<<<nbl, tb, 0, stream>>>(deg);
    // counting sort by degree (contention-free)
    k_lhist<<<NBLK, SCAN_B, 0, stream>>>(indeg, cnt);
    k_scan1<<<CNTB, SCAN_B, 0, stream>>>(cnt, bsum);
    k_scan2<<<1, 512, 0, stream>>>(bsum, CNTB);
    k_scan3<<<CNTB, SCAN_B, 0, stream>>>(cnt, bsum, cnt, -1, 0);
    k_rank<<<NBLK, SCAN_B, 0, stream>>>(indeg, cnt, perm, invperm, indegp);
    k_xp<<<nbl, tb, 0, stream>>>((const float2*)x, perm, xp);
    // CSR offsets over permuted nodes
    k_scan1<<<NBLK, SCAN_B, 0, stream>>>(indegp, bsum);
    k_scan2<<<1, 512, 0, stream>>>(bsum, NBLK);
    k_scan3<<<NBLK, SCAN_B, 0, stream>>>(indegp, bsum, offs, NTOT, NE);
    hipMemcpyAsync(cursor, offs, (size_t)NTOT * 4, hipMemcpyDeviceToDevice, stream);
    k_fill<<<ebl, tb, 0, stream>>>(row, col, wts, deg, invperm, cursor, adj);

    // ---- layer 1: 2 -> 32 ----
    {
        constexpr int FIN = 2;
        k_prop0_2<<<NB16, tb, 0, stream>>>((const float2*)xp, iw1, rw1, b1, offs, adj, OUTA);
        const unsigned* Hc = OUTA; unsigned* Hn = OUTB;
        for (int t = 1; t < TL - 1; ++t) {
            k_propt<FIN, false><<<KS * NB16, tb, 0, stream>>>(
                Hc, (const float*)xp, rw1 + (size_t)t * KS * FIN * HID,
                b1 + (size_t)t * KS * HID, w1 + (size_t)(t - 1) * KS * HID * HID,
                offs, adj, Hn, nullptr);
            const unsigned* tmp = Hc; Hc = Hn; Hn = (unsigned*)tmp;
        }
        k_propt<FIN, true><<<KS * NB16, tb, 0, stream>>>(
            Hc, (const float*)xp, rw1 + (size_t)(TL - 1) * KS * FIN * HID,
            b1 + (size_t)(TL - 1) * KS * HID, w1 + (size_t)(TL - 2) * KS * HID * HID,
            offs, adj, nullptr, xo);
        k_bnstats3<<<256, tb, 0, stream>>>(xo, xo + (size_t)NTOT * HID,
                                           xo + (size_t)2 * NTOT * HID, xa, stats);
        k_bnapply<<<NTOT * HID / tb, tb, 0, stream>>>(xa, stats, g1, be1, HID,
                                                      (unsigned short*)xplane);
    }
    // ---- layer 2: 32 -> 32 ----
    {
        constexpr int FIN = HID;
        k_prop0_32<<<NB16, tb, 0, stream>>>(xplane, xa, iw2, rw2, b2, offs, adj, OUTA);
        const unsigned* Hc = OUTA; unsigned* Hn = OUTB;
        for (int t = 1; t < TL - 1; ++t) {
            k_propt<FIN, false><<<KS * NB16, tb, 0, stream>>>(
                Hc, xa, rw2 + (size_t)t * KS * FIN * HID,
                b2 + (size_t)t * KS * HID, w2 + (size_t)(t - 1) * KS * HID * HID,
                offs, adj, Hn, nullptr);
            const unsigned* tmp = Hc; Hc = Hn; Hn = (unsigned*)tmp;
        }
        k_propt<FIN, true><<<KS * NB16, tb, 0, stream>>>(
            Hc, xa, rw2 + (size_t)(TL - 1) * KS * FIN * HID,
            b2 + (size_t)(TL - 1) * KS * HID, w2 + (size_t)(TL - 2) * KS * HID * HID,
            offs, adj, nullptr, xo);
        k_bnstats3<<<256, tb, 0, stream>>>(xo, xo + (size_t)NTOT * HID,
                                           xo + (size_t)2 * NTOT * HID, xb, stats + 2 * HID);
        k_bnapply<<<NTOT * HID / tb, tb, 0, stream>>>(xb, stats + 2 * HID, g2, be2, HID,
                                                      nullptr);
    }
    // ---- layer 3: 32 -> 1 ----
    {
        float4* HAf = (float4*)OUTA;
        float4* HBf = (float4*)OUTB;
        k_init1<<<nbl, tb, 0, stream>>>(xb, iw3, HAf);
        const float4* Hc = HAf; float4* Hn = HBf;
        for (int t = 0; t < TL - 1; ++t) {
            k_prop1<false><<<nbl, tb, 0, stream>>>(
                Hc, xb, rw3 + (size_t)t * KS * HID, b3 + (size_t)t * KS,
                w3 + (size_t)t * KS, offs, adj, perm, (float*)Hn);
            const float4* tmp = Hc; Hc = Hn; Hn = (float4*)tmp;
        }
        k_prop1<true><<<nbl, tb, 0, stream>>>(
            Hc, xb, rw3 + (size_t)(TL - 1) * KS * HID, b3 + (size_t)(TL - 1) * KS,
            nullptr, offs, adj, perm, xc);
        k_bnstats<<<256, tb, 0, stream>>>(xc, stats + 4 * HID, 1);
        k_bnapply<<<nbl, tb, 0, stream>>>(xc, stats + 4 * HID, g3, be3, 1, nullptr);
    }

    k_final<<<N_GRAPHS, 256, 0, stream>>>(xc, cw, cb, out);
}